// Round 2
// baseline (340.397 us; speedup 1.0000x reference)
//
#include <hip/hip_runtime.h>

typedef unsigned short u16;
typedef short  bf16x8 __attribute__((ext_vector_type(8)));
typedef u16    u16x8  __attribute__((ext_vector_type(8)));
typedef float  f32x4  __attribute__((ext_vector_type(4)));

__device__ __forceinline__ u16 f2bf(float f) {
  unsigned x = __float_as_uint(f);
  unsigned r = x + 0x7fffu + ((x >> 16) & 1u);   // RNE
  return (u16)(r >> 16);
}

__device__ __forceinline__ u16x8 cvt8(const float* __restrict__ p) {
  f32x4 lo = *(const f32x4*)p;
  f32x4 hi = *(const f32x4*)(p + 4);
  u16x8 o;
  o[0] = f2bf(lo[0]); o[1] = f2bf(lo[1]); o[2] = f2bf(lo[2]); o[3] = f2bf(lo[3]);
  o[4] = f2bf(hi[0]); o[5] = f2bf(hi[1]); o[6] = f2bf(hi[2]); o[7] = f2bf(hi[3]);
  return o;
}

// ---------------- GEMM: C[M,N] = A[M,K] * B[N,K]^T + bias --------------------
// A/B are fp32 (cast to bf16 in staging) or bf16, per template flags.
// 128x128 tile, BK=32, 4 waves (2x2), each wave 64x64 via 4x4 x (16x16x32 MFMA)
template<int N, int K, bool AF32, bool BF32, bool OUTF32>
__global__ __launch_bounds__(256) void gemm_bt(const void* __restrict__ Ap,
                                               const void* __restrict__ Bp,
                                               const float* __restrict__ bias,
                                               void* __restrict__ Cout) {
  __shared__ u16 As[128 * 32];
  __shared__ u16 Bs[128 * 32];
  const int tid = threadIdx.x;
  const int m0 = blockIdx.y * 128, n0 = blockIdx.x * 128;
  const int wave = tid >> 6, lane = tid & 63;
  const int c = lane & 15, g = lane >> 4;
  const int wm = (wave >> 1) * 64, wn = (wave & 1) * 64;
  f32x4 acc[4][4] = {};
  const int rowA = m0 + (tid >> 2), rowB = n0 + (tid >> 2);
  const int colK = (tid & 3) * 8;
  const int ldsOff = (tid >> 2) * 32 + colK;

  for (int k0 = 0; k0 < K; k0 += 32) {
    u16x8 a0, a1, b0, b1;
    if constexpr (AF32) {
      const float* A = (const float*)Ap;
      a0 = cvt8(&A[(size_t)rowA * K + colK + k0]);
      a1 = cvt8(&A[(size_t)(rowA + 64) * K + colK + k0]);
    } else {
      const u16* A = (const u16*)Ap;
      a0 = *(const u16x8*)&A[(size_t)rowA * K + colK + k0];
      a1 = *(const u16x8*)&A[(size_t)(rowA + 64) * K + colK + k0];
    }
    if constexpr (BF32) {
      const float* B = (const float*)Bp;
      b0 = cvt8(&B[(size_t)rowB * K + colK + k0]);
      b1 = cvt8(&B[(size_t)(rowB + 64) * K + colK + k0]);
    } else {
      const u16* B = (const u16*)Bp;
      b0 = *(const u16x8*)&B[(size_t)rowB * K + colK + k0];
      b1 = *(const u16x8*)&B[(size_t)(rowB + 64) * K + colK + k0];
    }
    __syncthreads();                       // protect LDS from prev-iter readers
    *(u16x8*)&As[ldsOff]        = a0;
    *(u16x8*)&As[ldsOff + 2048] = a1;
    *(u16x8*)&Bs[ldsOff]        = b0;
    *(u16x8*)&Bs[ldsOff + 2048] = b1;
    __syncthreads();
    bf16x8 af[4], bfr[4];
#pragma unroll
    for (int m = 0; m < 4; m++) af[m]  = *(const bf16x8*)&As[(wm + m * 16 + c) * 32 + g * 8];
#pragma unroll
    for (int n = 0; n < 4; n++) bfr[n] = *(const bf16x8*)&Bs[(wn + n * 16 + c) * 32 + g * 8];
#pragma unroll
    for (int m = 0; m < 4; m++)
#pragma unroll
      for (int n = 0; n < 4; n++)
        acc[m][n] = __builtin_amdgcn_mfma_f32_16x16x32_bf16(af[m], bfr[n], acc[m][n], 0, 0, 0);
  }

#pragma unroll
  for (int n = 0; n < 4; n++) {
    float bv = bias[n0 + wn + n * 16 + c];
#pragma unroll
    for (int m = 0; m < 4; m++) {
#pragma unroll
      for (int r = 0; r < 4; r++) {
        float val = acc[m][n][r] + bv;
        int row = m0 + wm + m * 16 + g * 4 + r;
        int col = n0 + wn + n * 16 + c;
        if constexpr (OUTF32) ((float*)Cout)[(size_t)row * N + col] = val;
        else                  ((u16*)Cout)[(size_t)row * N + col] = f2bf(val);
      }
    }
  }
}

// ---------------- V transpose: vt[h][d][s] = qkv[s][2048 + h*64 + d] ----------
__global__ __launch_bounds__(256) void transpose_v(const u16* __restrict__ qkv,
                                                   u16* __restrict__ vt) {
  __shared__ u16 tile[64][64];
  int h  = blockIdx.x >> 6;
  int s0 = (blockIdx.x & 63) * 64;
  int t = threadIdx.x;
  int row = t >> 3, ch = t & 7;
#pragma unroll
  for (int rep = 0; rep < 2; rep++) {
    int r = rep * 32 + row;
    u16x8 v = *(const u16x8*)&qkv[(size_t)(s0 + r) * 3072 + 2048 + h * 64 + ch * 8];
    *(u16x8*)&tile[r][ch * 8] = v;
  }
  __syncthreads();
#pragma unroll
  for (int rep = 0; rep < 2; rep++) {
    int d = rep * 32 + row;
    u16x8 w;
#pragma unroll
    for (int j = 0; j < 8; j++) w[j] = tile[ch * 8 + j][d];
    *(u16x8*)&vt[(size_t)(h * 64 + d) * 4096 + s0 + ch * 8] = w;
  }
}

// ---------------- flash attention, 1 wave/block, 32 q rows, k-tiles of 32 -----
// swapped QK^T: S^T = mfma(K, Q): lane(g,c) reg r -> S[k=k0+ks*16+g*4+r][q=q0+qs*16+c]
// O accumulator rows are q = qs*16 + g*4 + r  ->  all per-q factors (rescale al,
// final 1/l) must be broadcast per-register via __shfl(., g*4+r).
__global__ __launch_bounds__(64) void attn_kernel(const u16* __restrict__ qkv,
                                                  const u16* __restrict__ vt,
                                                  u16* __restrict__ ob) {
  const int bid = blockIdx.x;
  const int h = bid >> 7;
  const int q0 = (bid & 127) * 32;
  const int lane = threadIdx.x & 63;
  const int c = lane & 15, g = lane >> 4;
  __shared__ unsigned plds[32 * 20];   // P rows padded: stride 20 uints (80B)

  bf16x8 qf[2][2];
#pragma unroll
  for (int qs = 0; qs < 2; qs++)
#pragma unroll
    for (int dc = 0; dc < 2; dc++)
      qf[qs][dc] = *(const bf16x8*)&qkv[(size_t)(q0 + qs * 16 + c) * 3072 + h * 64 + dc * 32 + g * 8];

  f32x4 o[2][4] = {};
  float m[2]  = {-1e30f, -1e30f};
  float ls[2] = {0.f, 0.f};
  const u16* Kb = qkv + 1024 + h * 64;           // K row k: Kb[k*3072 + d]
  const u16* Vb = vt + (size_t)h * 64 * 4096;    // V^T row d: Vb[d*4096 + k]
  const f32x4 zero = {0.f, 0.f, 0.f, 0.f};

  for (int k0 = 0; k0 < 4096; k0 += 32) {
    bf16x8 kf[2][2];
#pragma unroll
    for (int ks = 0; ks < 2; ks++)
#pragma unroll
      for (int dc = 0; dc < 2; dc++)
        kf[ks][dc] = *(const bf16x8*)&Kb[(size_t)(k0 + ks * 16 + c) * 3072 + dc * 32 + g * 8];

    f32x4 st[2][2];
#pragma unroll
    for (int qs = 0; qs < 2; qs++)
#pragma unroll
      for (int ks = 0; ks < 2; ks++) {
        f32x4 s = __builtin_amdgcn_mfma_f32_16x16x32_bf16(kf[ks][0], qf[qs][0], zero, 0, 0, 0);
        st[qs][ks] = __builtin_amdgcn_mfma_f32_16x16x32_bf16(kf[ks][1], qf[qs][1], s, 0, 0, 0);
      }

#pragma unroll
    for (int qs = 0; qs < 2; qs++) {
      float s0 = st[qs][0][0], s1 = st[qs][0][1], s2 = st[qs][0][2], s3 = st[qs][0][3];
      float s4 = st[qs][1][0], s5 = st[qs][1][1], s6 = st[qs][1][2], s7 = st[qs][1][3];
      float tm = fmaxf(fmaxf(fmaxf(s0, s1), fmaxf(s2, s3)),
                       fmaxf(fmaxf(s4, s5), fmaxf(s6, s7)));
      tm = fmaxf(tm, __shfl_xor(tm, 16));
      tm = fmaxf(tm, __shfl_xor(tm, 32));      // tm = col-max for q-col c (uniform over g)
      float mn = fmaxf(m[qs], tm);
      float al = __expf(m[qs] - mn);           // rescale factor for q-col c
      m[qs] = mn;
      float p0 = __expf(s0 - mn), p1 = __expf(s1 - mn), p2 = __expf(s2 - mn), p3 = __expf(s3 - mn);
      float p4 = __expf(s4 - mn), p5 = __expf(s5 - mn), p6 = __expf(s6 - mn), p7 = __expf(s7 - mn);
      ls[qs] = ls[qs] * al + ((p0 + p1) + (p2 + p3)) + ((p4 + p5) + (p6 + p7));
      // FIX: O rows are q = qs*16 + g*4 + r -> broadcast al per register row.
      float alr[4];
#pragma unroll
      for (int r = 0; r < 4; r++) alr[r] = __shfl(al, g * 4 + r);
#pragma unroll
      for (int dt = 0; dt < 4; dt++)
#pragma unroll
        for (int r = 0; r < 4; r++) o[qs][dt][r] *= alr[r];
      unsigned base = (qs * 16 + c) * 20;
      plds[base + g * 2 + 0]     = (unsigned)f2bf(p0) | ((unsigned)f2bf(p1) << 16);
      plds[base + g * 2 + 1]     = (unsigned)f2bf(p2) | ((unsigned)f2bf(p3) << 16);
      plds[base + 8 + g * 2 + 0] = (unsigned)f2bf(p4) | ((unsigned)f2bf(p5) << 16);
      plds[base + 8 + g * 2 + 1] = (unsigned)f2bf(p6) | ((unsigned)f2bf(p7) << 16);
    }
    __syncthreads();   // single wave: orders LDS write->read

    bf16x8 pa[2];
#pragma unroll
    for (int qs = 0; qs < 2; qs++)
      pa[qs] = *(const bf16x8*)&plds[(qs * 16 + c) * 20 + g * 4];

    bf16x8 vf[4];
#pragma unroll
    for (int dt = 0; dt < 4; dt++)
      vf[dt] = *(const bf16x8*)&Vb[(size_t)(dt * 16 + c) * 4096 + k0 + g * 8];

#pragma unroll
    for (int qs = 0; qs < 2; qs++)
#pragma unroll
      for (int dt = 0; dt < 4; dt++)
        o[qs][dt] = __builtin_amdgcn_mfma_f32_16x16x32_bf16(pa[qs], vf[dt], o[qs][dt], 0, 0, 0);
    __syncthreads();   // WAR: next iter rewrites plds
  }

#pragma unroll
  for (int qs = 0; qs < 2; qs++) {
    float l = ls[qs];
    l += __shfl_xor(l, 16);
    l += __shfl_xor(l, 32);
    float inv[4];
#pragma unroll
    for (int r = 0; r < 4; r++) inv[r] = 1.0f / __shfl(l, g * 4 + r);
#pragma unroll
    for (int dt = 0; dt < 4; dt++) {
#pragma unroll
      for (int r = 0; r < 4; r++) {
        int row = q0 + qs * 16 + g * 4 + r;
        int col = h * 64 + dt * 16 + c;
        ob[(size_t)row * 1024 + col] = f2bf(o[qs][dt][r] * inv[r]);
      }
    }
  }
}

// ---------------- launch ------------------------------------------------------
extern "C" void kernel_launch(void* const* d_in, const int* in_sizes, int n_in,
                              void* d_out, int out_size, void* d_ws, size_t ws_size,
                              hipStream_t stream) {
  const float* x    = (const float*)d_in[0];
  const float* Wqkv = (const float*)d_in[1];
  const float* bqkv = (const float*)d_in[2];
  const float* Wout = (const float*)d_in[3];
  const float* bout = (const float*)d_in[4];

  char* ws = (char*)d_ws;
  u16* qkvb = (u16*)(ws);                            // 24 MB  [4096][3072]
  u16* vtb  = (u16*)(ws + (size_t)24 * (1u << 20));  //  8 MB  [16][64][4096]
  u16* obuf = (u16*)(ws + (size_t)32 * (1u << 20));  //  8 MB  [4096][1024]

  gemm_bt<3072, 1024, true, true, false><<<dim3(24, 32), 256, 0, stream>>>(x, Wqkv, bqkv, qkvb);

  transpose_v<<<1024, 256, 0, stream>>>(qkvb, vtb);

  attn_kernel<<<2048, 64, 0, stream>>>(qkvb, vtb, obuf);

  gemm_bt<1024, 1024, false, true, true><<<dim3(8, 32), 256, 0, stream>>>(obuf, Wout, bout, d_out);
}

// Round 3
// 334.322 us; speedup vs baseline: 1.0182x; 1.0182x over previous
//
#include <hip/hip_runtime.h>

typedef unsigned short u16;
typedef short  bf16x8 __attribute__((ext_vector_type(8)));
typedef u16    u16x8  __attribute__((ext_vector_type(8)));
typedef float  f32x4  __attribute__((ext_vector_type(4)));

__device__ __forceinline__ u16 f2bf(float f) {
  unsigned x = __float_as_uint(f);
  unsigned r = x + 0x7fffu + ((x >> 16) & 1u);   // RNE
  return (u16)(r >> 16);
}

__device__ __forceinline__ u16x8 cvt8(const float* __restrict__ p) {
  f32x4 lo = *(const f32x4*)p;
  f32x4 hi = *(const f32x4*)(p + 4);
  u16x8 o;
  o[0] = f2bf(lo[0]); o[1] = f2bf(lo[1]); o[2] = f2bf(lo[2]); o[3] = f2bf(lo[3]);
  o[4] = f2bf(hi[0]); o[5] = f2bf(hi[1]); o[6] = f2bf(hi[2]); o[7] = f2bf(hi[3]);
  return o;
}

// ---------------- GEMM: C[M,N] = A[M,K] * B[N,K]^T + bias --------------------
template<int N, int K, bool AF32, bool BF32, bool OUTF32>
__global__ __launch_bounds__(256) void gemm_bt(const void* __restrict__ Ap,
                                               const void* __restrict__ Bp,
                                               const float* __restrict__ bias,
                                               void* __restrict__ Cout) {
  __shared__ u16 As[128 * 32];
  __shared__ u16 Bs[128 * 32];
  const int tid = threadIdx.x;
  const int m0 = blockIdx.y * 128, n0 = blockIdx.x * 128;
  const int wave = tid >> 6, lane = tid & 63;
  const int c = lane & 15, g = lane >> 4;
  const int wm = (wave >> 1) * 64, wn = (wave & 1) * 64;
  f32x4 acc[4][4] = {};
  const int rowA = m0 + (tid >> 2), rowB = n0 + (tid >> 2);
  const int colK = (tid & 3) * 8;
  const int ldsOff = (tid >> 2) * 32 + colK;

  for (int k0 = 0; k0 < K; k0 += 32) {
    u16x8 a0, a1, b0, b1;
    if constexpr (AF32) {
      const float* A = (const float*)Ap;
      a0 = cvt8(&A[(size_t)rowA * K + colK + k0]);
      a1 = cvt8(&A[(size_t)(rowA + 64) * K + colK + k0]);
    } else {
      const u16* A = (const u16*)Ap;
      a0 = *(const u16x8*)&A[(size_t)rowA * K + colK + k0];
      a1 = *(const u16x8*)&A[(size_t)(rowA + 64) * K + colK + k0];
    }
    if constexpr (BF32) {
      const float* B = (const float*)Bp;
      b0 = cvt8(&B[(size_t)rowB * K + colK + k0]);
      b1 = cvt8(&B[(size_t)(rowB + 64) * K + colK + k0]);
    } else {
      const u16* B = (const u16*)Bp;
      b0 = *(const u16x8*)&B[(size_t)rowB * K + colK + k0];
      b1 = *(const u16x8*)&B[(size_t)(rowB + 64) * K + colK + k0];
    }
    __syncthreads();
    *(u16x8*)&As[ldsOff]        = a0;
    *(u16x8*)&As[ldsOff + 2048] = a1;
    *(u16x8*)&Bs[ldsOff]        = b0;
    *(u16x8*)&Bs[ldsOff + 2048] = b1;
    __syncthreads();
    bf16x8 af[4], bfr[4];
#pragma unroll
    for (int m = 0; m < 4; m++) af[m]  = *(const bf16x8*)&As[(wm + m * 16 + c) * 32 + g * 8];
#pragma unroll
    for (int n = 0; n < 4; n++) bfr[n] = *(const bf16x8*)&Bs[(wn + n * 16 + c) * 32 + g * 8];
#pragma unroll
    for (int m = 0; m < 4; m++)
#pragma unroll
      for (int n = 0; n < 4; n++)
        acc[m][n] = __builtin_amdgcn_mfma_f32_16x16x32_bf16(af[m], bfr[n], acc[m][n], 0, 0, 0);
  }

#pragma unroll
  for (int n = 0; n < 4; n++) {
    float bv = bias[n0 + wn + n * 16 + c];
#pragma unroll
    for (int m = 0; m < 4; m++) {
#pragma unroll
      for (int r = 0; r < 4; r++) {
        float val = acc[m][n][r] + bv;
        int row = m0 + wm + m * 16 + g * 4 + r;
        int col = n0 + wn + n * 16 + c;
        if constexpr (OUTF32) ((float*)Cout)[(size_t)row * N + col] = val;
        else                  ((u16*)Cout)[(size_t)row * N + col] = f2bf(val);
      }
    }
  }
}

// ---------------- V transpose: vt[h][d][s] = qkv[s][2048 + h*64 + d] ----------
__global__ __launch_bounds__(256) void transpose_v(const u16* __restrict__ qkv,
                                                   u16* __restrict__ vt) {
  __shared__ u16 tile[64][64];
  int h  = blockIdx.x >> 6;
  int s0 = (blockIdx.x & 63) * 64;
  int t = threadIdx.x;
  int row = t >> 3, ch = t & 7;
#pragma unroll
  for (int rep = 0; rep < 2; rep++) {
    int r = rep * 32 + row;
    u16x8 v = *(const u16x8*)&qkv[(size_t)(s0 + r) * 3072 + 2048 + h * 64 + ch * 8];
    *(u16x8*)&tile[r][ch * 8] = v;
  }
  __syncthreads();
#pragma unroll
  for (int rep = 0; rep < 2; rep++) {
    int d = rep * 32 + row;
    u16x8 w;
#pragma unroll
    for (int j = 0; j < 8; j++) w[j] = tile[ch * 8 + j][d];
    *(u16x8*)&vt[(size_t)(h * 64 + d) * 4096 + s0 + ch * 8] = w;
  }
}

// ---------------- flash attention, 1 wave/block, 32 q rows, KVBLK=64 ---------
// swapped QK^T: lane(g,c) reg r of st[ks] -> S[k=k0+ks*16+g*4+r][q=q0+qs*16+c]
// O/accl accumulator rows are q = qs*16 + g*4 + r (per-register).
__device__ __forceinline__ void attn_tile(
    int k0, int k1,
    const u16* __restrict__ Kb, const u16* __restrict__ Vb,
    const bf16x8 (&qf)[2][2],
    bf16x8 (&kf)[4][2], bf16x8 (&kfn)[4][2],
    f32x4 (&o)[2][4], f32x4 (&accl)[2], float (&m)[2],
    unsigned* __restrict__ plds, int c, int g, bf16x8 ones)
{
  // issue V loads for this tile + K loads for next tile (prefetch)
  bf16x8 vf[2][4];
#pragma unroll
  for (int kk = 0; kk < 2; kk++)
#pragma unroll
    for (int dt = 0; dt < 4; dt++)
      vf[kk][dt] = *(const bf16x8*)&Vb[(size_t)(dt * 16 + c) * 4096 + k0 + kk * 32 + g * 8];
#pragma unroll
  for (int ks = 0; ks < 4; ks++)
#pragma unroll
    for (int dc = 0; dc < 2; dc++)
      kfn[ks][dc] = *(const bf16x8*)&Kb[(size_t)(k1 + ks * 16 + c) * 3072 + dc * 32 + g * 8];

  const f32x4 zero = {0.f, 0.f, 0.f, 0.f};
#pragma unroll
  for (int qs = 0; qs < 2; qs++) {
    f32x4 st[4];
    __builtin_amdgcn_s_setprio(1);
#pragma unroll
    for (int ks = 0; ks < 4; ks++) {
      f32x4 s = __builtin_amdgcn_mfma_f32_16x16x32_bf16(kf[ks][0], qf[qs][0], zero, 0, 0, 0);
      st[ks]  = __builtin_amdgcn_mfma_f32_16x16x32_bf16(kf[ks][1], qf[qs][1], s, 0, 0, 0);
    }
    __builtin_amdgcn_s_setprio(0);
    // tile max for q-col c (uniform over g after xor-reduce)
    float t0 = fmaxf(fmaxf(fmaxf(st[0][0], st[0][1]), st[0][2]),
                     fmaxf(fmaxf(st[0][3], st[1][0]), st[1][1]));
    float t1 = fmaxf(fmaxf(fmaxf(st[1][2], st[1][3]), st[2][0]),
                     fmaxf(fmaxf(st[2][1], st[2][2]), st[2][3]));
    float t2 = fmaxf(fmaxf(st[3][0], st[3][1]), fmaxf(st[3][2], st[3][3]));
    float tm = fmaxf(fmaxf(t0, t1), t2);
    tm = fmaxf(tm, __shfl_xor(tm, 16));
    tm = fmaxf(tm, __shfl_xor(tm, 32));
    if (__any(tm > m[qs] + 8.f)) {             // defer-max: rescale only when needed
      float mn = fmaxf(m[qs], tm);
      float al = __expf(m[qs] - mn);
      m[qs] = mn;
      float alr[4];
#pragma unroll
      for (int r = 0; r < 4; r++) alr[r] = __shfl(al, g * 4 + r);
#pragma unroll
      for (int dt = 0; dt < 4; dt++)
#pragma unroll
        for (int r = 0; r < 4; r++) o[qs][dt][r] *= alr[r];
#pragma unroll
      for (int r = 0; r < 4; r++) accl[qs][r] *= alr[r];
    }
    float mm = m[qs];
    unsigned base = (unsigned)(qs * 16 + c) * 36 + g * 2;
#pragma unroll
    for (int ks = 0; ks < 4; ks++) {
      float p0 = __expf(st[ks][0] - mm), p1 = __expf(st[ks][1] - mm);
      float p2 = __expf(st[ks][2] - mm), p3 = __expf(st[ks][3] - mm);
      unsigned w0, w1;
      asm("v_cvt_pk_bf16_f32 %0, %1, %2" : "=v"(w0) : "v"(p0), "v"(p1));
      asm("v_cvt_pk_bf16_f32 %0, %1, %2" : "=v"(w1) : "v"(p2), "v"(p3));
      plds[base + ks * 8]     = w0;
      plds[base + ks * 8 + 1] = w1;
    }
  }
  __syncthreads();   // P writes -> reads (single wave: compiles to waitcnt)

  bf16x8 pa[2][2];
#pragma unroll
  for (int qs = 0; qs < 2; qs++)
#pragma unroll
    for (int hh = 0; hh < 2; hh++)
      pa[qs][hh] = *(const bf16x8*)&plds[(qs * 16 + c) * 36 + hh * 16 + g * 4];

  __builtin_amdgcn_s_setprio(1);
#pragma unroll
  for (int qs = 0; qs < 2; qs++) {
#pragma unroll
    for (int dt = 0; dt < 4; dt++) {
      o[qs][dt] = __builtin_amdgcn_mfma_f32_16x16x32_bf16(pa[qs][0], vf[0][dt], o[qs][dt], 0, 0, 0);
      o[qs][dt] = __builtin_amdgcn_mfma_f32_16x16x32_bf16(pa[qs][1], vf[1][dt], o[qs][dt], 0, 0, 0);
    }
    // denominator: sum_k P[q][k] via ones-column MFMA; lands row-aligned with O
    accl[qs] = __builtin_amdgcn_mfma_f32_16x16x32_bf16(pa[qs][0], ones, accl[qs], 0, 0, 0);
    accl[qs] = __builtin_amdgcn_mfma_f32_16x16x32_bf16(pa[qs][1], ones, accl[qs], 0, 0, 0);
  }
  __builtin_amdgcn_s_setprio(0);
  __syncthreads();   // WAR before next tile rewrites plds
}

__global__ __launch_bounds__(64) void attn_kernel(const u16* __restrict__ qkv,
                                                  const u16* __restrict__ vt,
                                                  u16* __restrict__ ob) {
  const int bid = blockIdx.x;
  const int h = bid >> 7;
  const int q0 = (bid & 127) * 32;
  const int lane = threadIdx.x & 63;
  const int c = lane & 15, g = lane >> 4;
  __shared__ unsigned plds[32 * 36];   // [qs*16+c][36] u32, 64 k-vals + pad

  bf16x8 qf[2][2];
#pragma unroll
  for (int qs = 0; qs < 2; qs++)
#pragma unroll
    for (int dc = 0; dc < 2; dc++)
      qf[qs][dc] = *(const bf16x8*)&qkv[(size_t)(q0 + qs * 16 + c) * 3072 + h * 64 + dc * 32 + g * 8];

  bf16x8 ones;
#pragma unroll
  for (int j = 0; j < 8; j++) ones[j] = (short)0x3F80;   // bf16 1.0

  f32x4 o[2][4] = {};
  f32x4 accl[2] = {};
  float m[2] = {-1e9f, -1e9f};
  const u16* Kb = qkv + 1024 + h * 64;
  const u16* Vb = vt + (size_t)h * 64 * 4096;

  bf16x8 kfA[4][2], kfB[4][2];
#pragma unroll
  for (int ks = 0; ks < 4; ks++)
#pragma unroll
    for (int dc = 0; dc < 2; dc++)
      kfA[ks][dc] = *(const bf16x8*)&Kb[(size_t)(ks * 16 + c) * 3072 + dc * 32 + g * 8];

  for (int k0 = 0; k0 < 4096; k0 += 128) {
    attn_tile(k0,      k0 + 64,           Kb, Vb, qf, kfA, kfB, o, accl, m, plds, c, g, ones);
    attn_tile(k0 + 64, (k0 + 128) & 4095, Kb, Vb, qf, kfB, kfA, o, accl, m, plds, c, g, ones);
  }

#pragma unroll
  for (int qs = 0; qs < 2; qs++) {
#pragma unroll
    for (int r = 0; r < 4; r++) {
      float inv = 1.0f / accl[qs][r];
#pragma unroll
      for (int dt = 0; dt < 4; dt++) {
        int row = q0 + qs * 16 + g * 4 + r;
        int col = h * 64 + dt * 16 + c;
        ob[(size_t)row * 1024 + col] = f2bf(o[qs][dt][r] * inv);
      }
    }
  }
}

// ---------------- launch ------------------------------------------------------
extern "C" void kernel_launch(void* const* d_in, const int* in_sizes, int n_in,
                              void* d_out, int out_size, void* d_ws, size_t ws_size,
                              hipStream_t stream) {
  const float* x    = (const float*)d_in[0];
  const float* Wqkv = (const float*)d_in[1];
  const float* bqkv = (const float*)d_in[2];
  const float* Wout = (const float*)d_in[3];
  const float* bout = (const float*)d_in[4];

  char* ws = (char*)d_ws;
  u16* qkvb = (u16*)(ws);                            // 24 MB  [4096][3072]
  u16* vtb  = (u16*)(ws + (size_t)24 * (1u << 20));  //  8 MB  [16][64][4096]
  u16* obuf = (u16*)(ws + (size_t)32 * (1u << 20));  //  8 MB  [4096][1024]

  gemm_bt<3072, 1024, true, true, false><<<dim3(24, 32), 256, 0, stream>>>(x, Wqkv, bqkv, qkvb);

  transpose_v<<<1024, 256, 0, stream>>>(qkvb, vtb);

  attn_kernel<<<2048, 64, 0, stream>>>(qkvb, vtb, obuf);

  gemm_bt<1024, 1024, false, true, true><<<dim3(8, 32), 256, 0, stream>>>(obuf, Wout, bout, d_out);
}

// Round 4
// 222.146 us; speedup vs baseline: 1.5323x; 1.5050x over previous
//
#include <hip/hip_runtime.h>

typedef unsigned short u16;
typedef short  bf16x8 __attribute__((ext_vector_type(8)));
typedef u16    u16x8  __attribute__((ext_vector_type(8)));
typedef float  f32x4  __attribute__((ext_vector_type(4)));

__device__ __forceinline__ u16 f2bf(float f) {
  unsigned x = __float_as_uint(f);
  unsigned r = x + 0x7fffu + ((x >> 16) & 1u);   // RNE
  return (u16)(r >> 16);
}

__device__ __forceinline__ u16x8 cvt8(const float* __restrict__ p) {
  f32x4 lo = *(const f32x4*)p;
  f32x4 hi = *(const f32x4*)(p + 4);
  u16x8 o;
  o[0] = f2bf(lo[0]); o[1] = f2bf(lo[1]); o[2] = f2bf(lo[2]); o[3] = f2bf(lo[3]);
  o[4] = f2bf(hi[0]); o[5] = f2bf(hi[1]); o[6] = f2bf(hi[2]); o[7] = f2bf(hi[3]);
  return o;
}

// ---------------- GEMM: C[M,N] = A[M,K] * B[N,K]^T + bias --------------------
template<int N, int K, bool AF32, bool BF32, bool OUTF32>
__global__ __launch_bounds__(256) void gemm_bt(const void* __restrict__ Ap,
                                               const void* __restrict__ Bp,
                                               const float* __restrict__ bias,
                                               void* __restrict__ Cout) {
  __shared__ u16 As[128 * 32];
  __shared__ u16 Bs[128 * 32];
  const int tid = threadIdx.x;
  const int m0 = blockIdx.y * 128, n0 = blockIdx.x * 128;
  const int wave = tid >> 6, lane = tid & 63;
  const int c = lane & 15, g = lane >> 4;
  const int wm = (wave >> 1) * 64, wn = (wave & 1) * 64;
  f32x4 acc[4][4] = {};
  const int rowA = m0 + (tid >> 2), rowB = n0 + (tid >> 2);
  const int colK = (tid & 3) * 8;
  const int ldsOff = (tid >> 2) * 32 + colK;

  for (int k0 = 0; k0 < K; k0 += 32) {
    u16x8 a0, a1, b0, b1;
    if constexpr (AF32) {
      const float* A = (const float*)Ap;
      a0 = cvt8(&A[(size_t)rowA * K + colK + k0]);
      a1 = cvt8(&A[(size_t)(rowA + 64) * K + colK + k0]);
    } else {
      const u16* A = (const u16*)Ap;
      a0 = *(const u16x8*)&A[(size_t)rowA * K + colK + k0];
      a1 = *(const u16x8*)&A[(size_t)(rowA + 64) * K + colK + k0];
    }
    if constexpr (BF32) {
      const float* B = (const float*)Bp;
      b0 = cvt8(&B[(size_t)rowB * K + colK + k0]);
      b1 = cvt8(&B[(size_t)(rowB + 64) * K + colK + k0]);
    } else {
      const u16* B = (const u16*)Bp;
      b0 = *(const u16x8*)&B[(size_t)rowB * K + colK + k0];
      b1 = *(const u16x8*)&B[(size_t)(rowB + 64) * K + colK + k0];
    }
    __syncthreads();
    *(u16x8*)&As[ldsOff]        = a0;
    *(u16x8*)&As[ldsOff + 2048] = a1;
    *(u16x8*)&Bs[ldsOff]        = b0;
    *(u16x8*)&Bs[ldsOff + 2048] = b1;
    __syncthreads();
    bf16x8 af[4], bfr[4];
#pragma unroll
    for (int m = 0; m < 4; m++) af[m]  = *(const bf16x8*)&As[(wm + m * 16 + c) * 32 + g * 8];
#pragma unroll
    for (int n = 0; n < 4; n++) bfr[n] = *(const bf16x8*)&Bs[(wn + n * 16 + c) * 32 + g * 8];
#pragma unroll
    for (int m = 0; m < 4; m++)
#pragma unroll
      for (int n = 0; n < 4; n++)
        acc[m][n] = __builtin_amdgcn_mfma_f32_16x16x32_bf16(af[m], bfr[n], acc[m][n], 0, 0, 0);
  }

#pragma unroll
  for (int n = 0; n < 4; n++) {
    float bv = bias[n0 + wn + n * 16 + c];
#pragma unroll
    for (int m = 0; m < 4; m++) {
#pragma unroll
      for (int r = 0; r < 4; r++) {
        float val = acc[m][n][r] + bv;
        int row = m0 + wm + m * 16 + g * 4 + r;
        int col = n0 + wn + n * 16 + c;
        if constexpr (OUTF32) ((float*)Cout)[(size_t)row * N + col] = val;
        else                  ((u16*)Cout)[(size_t)row * N + col] = f2bf(val);
      }
    }
  }
}

// ---------------- V transpose: vt[h][d][s] = qkv[s][2048 + h*64 + d] ----------
__global__ __launch_bounds__(256) void transpose_v(const u16* __restrict__ qkv,
                                                   u16* __restrict__ vt) {
  __shared__ u16 tile[64][64];
  int h  = blockIdx.x >> 6;
  int s0 = (blockIdx.x & 63) * 64;
  int t = threadIdx.x;
  int row = t >> 3, ch = t & 7;
#pragma unroll
  for (int rep = 0; rep < 2; rep++) {
    int r = rep * 32 + row;
    u16x8 v = *(const u16x8*)&qkv[(size_t)(s0 + r) * 3072 + 2048 + h * 64 + ch * 8];
    *(u16x8*)&tile[r][ch * 8] = v;
  }
  __syncthreads();
#pragma unroll
  for (int rep = 0; rep < 2; rep++) {
    int d = rep * 32 + row;
    u16x8 w;
#pragma unroll
    for (int j = 0; j < 8; j++) w[j] = tile[ch * 8 + j][d];
    *(u16x8*)&vt[(size_t)(h * 64 + d) * 4096 + s0 + ch * 8] = w;
  }
}

// ---------------- flash attention: 4 waves/block, 128 q-rows, KVBLK=64 -------
// K/V staged cooperatively in XOR-swizzled double-buffered LDS.
// swapped QK^T: lane(g,c) reg r of st[ks] -> S[k=k0+ks*16+g*4+r][q=qw+qs*16+c]
// O/accl accumulator rows are q = qw + qs*16 + g*4 + r (per-register).
__global__ __launch_bounds__(256) void attn_kernel(const u16* __restrict__ qkv,
                                                   const u16* __restrict__ vt,
                                                   u16* __restrict__ ob) {
  const int bid = blockIdx.x;
  const int h  = bid >> 5;
  const int q0 = (bid & 31) * 128;
  const int tid = threadIdx.x;
  const int wave = tid >> 6, lane = tid & 63;
  const int c = lane & 15, g = lane >> 4;
  const int qw = q0 + wave * 32;

  __shared__ u16 kls[2][64 * 64];          // 16 KB  K tiles (swizzled)
  __shared__ u16 vls[2][64 * 64];          // 16 KB  V^T tiles (swizzled)
  __shared__ unsigned plds[4][32 * 36];    // 18 KB  per-wave P buffers
  unsigned* pw = plds[wave];

  // staging slots: 512 granules (64 rows x 8 x 16B) per tile, 2 per thread
  const int srow0 = tid >> 3, sgr = tid & 7;
  const int srow1 = srow0 + 32;
  const int sdst0 = srow0 * 64 + ((sgr ^ (srow0 & 7)) << 3);
  const int sdst1 = srow1 * 64 + ((sgr ^ (srow1 & 7)) << 3);
  const u16* Kg = qkv + 1024 + h * 64;             // + k*3072 + sgr*8
  const u16* Vg = vt + (size_t)h * 64 * 4096;      // + d*4096 + k + sgr*8

  bf16x8 qf[2][2];
#pragma unroll
  for (int qs = 0; qs < 2; qs++)
#pragma unroll
    for (int dc = 0; dc < 2; dc++)
      qf[qs][dc] = *(const bf16x8*)&qkv[(size_t)(qw + qs * 16 + c) * 3072 + h * 64 + dc * 32 + g * 8];

  bf16x8 ones;
#pragma unroll
  for (int j = 0; j < 8; j++) ones[j] = (short)0x3F80;   // bf16 1.0

  f32x4 o[2][4] = {};
  f32x4 accl[2] = {};
  float m[2] = {-1e9f, -1e9f};
  const f32x4 zero = {0.f, 0.f, 0.f, 0.f};

  // prologue: stage tile 0
  {
    u16x8 ka = *(const u16x8*)&Kg[(size_t)srow0 * 3072 + sgr * 8];
    u16x8 kb = *(const u16x8*)&Kg[(size_t)srow1 * 3072 + sgr * 8];
    u16x8 va = *(const u16x8*)&Vg[(size_t)srow0 * 4096 + sgr * 8];
    u16x8 vb = *(const u16x8*)&Vg[(size_t)srow1 * 4096 + sgr * 8];
    *(u16x8*)&kls[0][sdst0] = ka;
    *(u16x8*)&kls[0][sdst1] = kb;
    *(u16x8*)&vls[0][sdst0] = va;
    *(u16x8*)&vls[0][sdst1] = vb;
  }
  __syncthreads();

  for (int t = 0; t < 64; ++t) {
    const int cur = t & 1;
    const int k0 = t * 64;
    const int kn = (k0 + 64) & 4095;     // wrap keeps loads branchless (last write unused)

    // T14: issue next-tile global loads early; writes land after compute
    u16x8 nka = *(const u16x8*)&Kg[(size_t)(kn + srow0) * 3072 + sgr * 8];
    u16x8 nkb = *(const u16x8*)&Kg[(size_t)(kn + srow1) * 3072 + sgr * 8];
    u16x8 nva = *(const u16x8*)&Vg[(size_t)srow0 * 4096 + kn + sgr * 8];
    u16x8 nvb = *(const u16x8*)&Vg[(size_t)srow1 * 4096 + kn + sgr * 8];

    // fragments from swizzled LDS (row&7 == c&7 for all fragment rows)
    bf16x8 kf[4][2];
#pragma unroll
    for (int ks = 0; ks < 4; ks++)
#pragma unroll
      for (int dc = 0; dc < 2; dc++)
        kf[ks][dc] = *(const bf16x8*)&kls[cur][(ks * 16 + c) * 64 + (((dc * 4 + g) ^ (c & 7)) << 3)];
    bf16x8 vf[2][4];
#pragma unroll
    for (int kk = 0; kk < 2; kk++)
#pragma unroll
      for (int dt = 0; dt < 4; dt++)
        vf[kk][dt] = *(const bf16x8*)&vls[cur][(dt * 16 + c) * 64 + (((kk * 4 + g) ^ (c & 7)) << 3)];

#pragma unroll
    for (int qs = 0; qs < 2; qs++) {
      f32x4 st[4];
      __builtin_amdgcn_s_setprio(1);
#pragma unroll
      for (int ks = 0; ks < 4; ks++) {
        f32x4 s = __builtin_amdgcn_mfma_f32_16x16x32_bf16(kf[ks][0], qf[qs][0], zero, 0, 0, 0);
        st[ks]  = __builtin_amdgcn_mfma_f32_16x16x32_bf16(kf[ks][1], qf[qs][1], s, 0, 0, 0);
      }
      __builtin_amdgcn_s_setprio(0);
      float t0 = fmaxf(fmaxf(fmaxf(st[0][0], st[0][1]), st[0][2]),
                       fmaxf(fmaxf(st[0][3], st[1][0]), st[1][1]));
      float t1 = fmaxf(fmaxf(fmaxf(st[1][2], st[1][3]), st[2][0]),
                       fmaxf(fmaxf(st[2][1], st[2][2]), st[2][3]));
      float t2 = fmaxf(fmaxf(st[3][0], st[3][1]), fmaxf(st[3][2], st[3][3]));
      float tm = fmaxf(fmaxf(t0, t1), t2);
      tm = fmaxf(tm, __shfl_xor(tm, 16));
      tm = fmaxf(tm, __shfl_xor(tm, 32));      // col-max for q-col c
      if (__any(tm > m[qs] + 8.f)) {           // defer-max (T13)
        float mn = fmaxf(m[qs], tm);
        float al = __expf(m[qs] - mn);
        m[qs] = mn;
        float alr[4];
#pragma unroll
        for (int r = 0; r < 4; r++) alr[r] = __shfl(al, g * 4 + r);
#pragma unroll
        for (int dt = 0; dt < 4; dt++)
#pragma unroll
          for (int r = 0; r < 4; r++) o[qs][dt][r] *= alr[r];
#pragma unroll
        for (int r = 0; r < 4; r++) accl[qs][r] *= alr[r];
      }
      float mm = m[qs];
      unsigned base = (unsigned)(qs * 16 + c) * 36 + g * 2;
#pragma unroll
      for (int ks = 0; ks < 4; ks++) {
        float p0 = __expf(st[ks][0] - mm), p1 = __expf(st[ks][1] - mm);
        float p2 = __expf(st[ks][2] - mm), p3 = __expf(st[ks][3] - mm);
        unsigned w0, w1;
        asm("v_cvt_pk_bf16_f32 %0, %1, %2" : "=v"(w0) : "v"(p0), "v"(p1));
        asm("v_cvt_pk_bf16_f32 %0, %1, %2" : "=v"(w1) : "v"(p2), "v"(p3));
        pw[base + ks * 8]     = w0;
        pw[base + ks * 8 + 1] = w1;
      }
    }
    // pw is wave-private; compiler-inserted lgkmcnt orders write->read

    bf16x8 pa[2][2];
#pragma unroll
    for (int qs = 0; qs < 2; qs++)
#pragma unroll
      for (int hh = 0; hh < 2; hh++)
        pa[qs][hh] = *(const bf16x8*)&pw[(qs * 16 + c) * 36 + hh * 16 + g * 4];

    __builtin_amdgcn_s_setprio(1);
#pragma unroll
    for (int qs = 0; qs < 2; qs++) {
#pragma unroll
      for (int dt = 0; dt < 4; dt++) {
        o[qs][dt] = __builtin_amdgcn_mfma_f32_16x16x32_bf16(pa[qs][0], vf[0][dt], o[qs][dt], 0, 0, 0);
        o[qs][dt] = __builtin_amdgcn_mfma_f32_16x16x32_bf16(pa[qs][1], vf[1][dt], o[qs][dt], 0, 0, 0);
      }
      accl[qs] = __builtin_amdgcn_mfma_f32_16x16x32_bf16(pa[qs][0], ones, accl[qs], 0, 0, 0);
      accl[qs] = __builtin_amdgcn_mfma_f32_16x16x32_bf16(pa[qs][1], ones, accl[qs], 0, 0, 0);
    }
    __builtin_amdgcn_s_setprio(0);

    // write staged tile t+1 into the other buffer (no reader this iter)
    *(u16x8*)&kls[cur ^ 1][sdst0] = nka;
    *(u16x8*)&kls[cur ^ 1][sdst1] = nkb;
    *(u16x8*)&vls[cur ^ 1][sdst0] = nva;
    *(u16x8*)&vls[cur ^ 1][sdst1] = nvb;
    __syncthreads();
  }

#pragma unroll
  for (int qs = 0; qs < 2; qs++) {
#pragma unroll
    for (int r = 0; r < 4; r++) {
      float inv = 1.0f / accl[qs][r];
#pragma unroll
      for (int dt = 0; dt < 4; dt++) {
        int row = qw + qs * 16 + g * 4 + r;
        int col = h * 64 + dt * 16 + c;
        ob[(size_t)row * 1024 + col] = f2bf(o[qs][dt][r] * inv);
      }
    }
  }
}

// ---------------- launch ------------------------------------------------------
extern "C" void kernel_launch(void* const* d_in, const int* in_sizes, int n_in,
                              void* d_out, int out_size, void* d_ws, size_t ws_size,
                              hipStream_t stream) {
  const float* x    = (const float*)d_in[0];
  const float* Wqkv = (const float*)d_in[1];
  const float* bqkv = (const float*)d_in[2];
  const float* Wout = (const float*)d_in[3];
  const float* bout = (const float*)d_in[4];

  char* ws = (char*)d_ws;
  u16* qkvb = (u16*)(ws);                            // 24 MB  [4096][3072]
  u16* vtb  = (u16*)(ws + (size_t)24 * (1u << 20));  //  8 MB  [16][64][4096]
  u16* obuf = (u16*)(ws + (size_t)32 * (1u << 20));  //  8 MB  [4096][1024]

  gemm_bt<3072, 1024, true, true, false><<<dim3(24, 32), 256, 0, stream>>>(x, Wqkv, bqkv, qkvb);

  transpose_v<<<1024, 256, 0, stream>>>(qkvb, vtb);

  attn_kernel<<<512, 256, 0, stream>>>(qkvb, vtb, obuf);

  gemm_bt<1024, 1024, false, true, true><<<dim3(8, 32), 256, 0, stream>>>(obuf, Wout, bout, d_out);
}